// Round 11
// baseline (50.808 us; speedup 1.0000x reference)
//
#include <hip/hip_runtime.h>
#include <hip/hip_bf16.h>

#define NN 7
#define HH 16
#define RR 64
#define CC 8
#define NBINS (NN * RR * NN)   // 3136

#define HIST_BLOCK 1024
#define HIST_GRID  256                      // 1 block/CU, 16 waves/CU, 128-VGPR budget
#define NT (HIST_GRID * HIST_BLOCK)         // 262144 threads
#define NSLOT 8                             // ceil(E4/NT) = 8 for E=8M

#define RED_GRID 50                         // block 0 = finisher, 1..49 = reducers

// ---------------------------------------------------------------------------
// Kernel 1: histogram edges into (dst, rel, src) bins in LDS (R10 verbatim:
// rolling depth-4 pipeline over 8 slots, in-flight loads never drain to 0).
// Block 0 additionally zeroes the ticket counter for kernel 2 (poison-immune,
// re-zeroed every call -> replay-deterministic).
// ---------------------------------------------------------------------------
__global__ __launch_bounds__(HIST_BLOCK) void rgcn_hist(
    const int* __restrict__ src, const int* __restrict__ dst,
    const int* __restrict__ et, int E, int* __restrict__ part,
    int* __restrict__ ctrl) {
    __shared__ int bins[NBINS];
    if (blockIdx.x == 0 && threadIdx.x == 0)
        __hip_atomic_store(&ctrl[0], 0, __ATOMIC_RELAXED, __HIP_MEMORY_SCOPE_AGENT);
    for (int i = threadIdx.x; i < NBINS; i += HIST_BLOCK) bins[i] = 0;
    __syncthreads();

    const int tid = blockIdx.x * HIST_BLOCK + threadIdx.x;
    const int E4 = E >> 2;
    const int4* s4 = reinterpret_cast<const int4*>(src);
    const int4* d4 = reinterpret_cast<const int4*>(dst);
    const int4* t4 = reinterpret_cast<const int4*>(et);

    if (E4 > 0) {
        for (int base = tid; base < E4; base += NSLOT * NT) {
            int4 S[4], D[4], T[4];
            // prologue: 12 loads back-to-back (slots 0-3, clamped)
#pragma unroll
            for (int k = 0; k < 4; ++k) {
                int idx = base + k * NT;
                int cl = idx < E4 ? idx : (E4 - 1);
                S[k] = s4[cl]; D[k] = d4[cl]; T[k] = t4[cl];
            }
            // steady state: consume slot k, reissue slot k+4 into same regs
#pragma unroll
            for (int k = 0; k < NSLOT; ++k) {
                const int slot = k & 3;
                const int add = (base + k * NT < E4) ? 1 : 0;  // predicate OOB
                atomicAdd(&bins[D[slot].x * (RR * NN) + T[slot].x * NN + S[slot].x], add);
                atomicAdd(&bins[D[slot].y * (RR * NN) + T[slot].y * NN + S[slot].y], add);
                atomicAdd(&bins[D[slot].z * (RR * NN) + T[slot].z * NN + S[slot].z], add);
                atomicAdd(&bins[D[slot].w * (RR * NN) + T[slot].w * NN + S[slot].w], add);
                if (k < NSLOT - 4) {
                    int idx = base + (k + 4) * NT;
                    int cl = idx < E4 ? idx : (E4 - 1);
                    S[slot] = s4[cl]; D[slot] = d4[cl]; T[slot] = t4[cl];
                }
            }
        }
    }
    // scalar tail (E not multiple of 4; never runs for E=8M)
    for (int e = (E4 << 2) + tid; e < E; e += NT) {
        atomicAdd(&bins[dst[e] * (RR * NN) + et[e] * NN + src[e]], 1);
    }

    __syncthreads();
    // plain coalesced store of the whole private histogram, vectorized
    int4* slice4 = reinterpret_cast<int4*>(part + blockIdx.x * NBINS);
    const int4* bins4 = reinterpret_cast<const int4*>(bins);
    for (int i2 = threadIdx.x; i2 < NBINS / 4; i2 += HIST_BLOCK)
        slice4[i2] = bins4[i2];
}

// ---------------------------------------------------------------------------
// Kernel 2: fused reduce + finish.
//   blocks 1..49: reduce 64 bins each (256 partials), store gbins, ticket++.
//   block 0:      stage W1/W2 into LDS (in parallel with reducers), spin on
//                 ticket==49, then run the finish phases (R10 logic).
// Reducers never wait -> deadlock-free regardless of residency.
// ---------------------------------------------------------------------------
__global__ __launch_bounds__(1024) void rgcn_redfin(
    const int* __restrict__ part, int* __restrict__ gbins,
    int* __restrict__ ctrl,
    const float* __restrict__ W1,    // [R][N][H]
    const float* __restrict__ root1, // [N][H]
    const float* __restrict__ b1,    // [H]
    const float* __restrict__ W2,    // [R][H][C]
    const float* __restrict__ root2, // [H][C]
    const float* __restrict__ b2,    // [C]
    float* __restrict__ out) {       // [N][C]
    __shared__ float w1s[RR * NN * HH]; // 28 KB
    __shared__ float w2s[RR * HH * CC]; // 32 KB
    __shared__ int   redacc[16][64];
    __shared__ float cntf[NN][RR][NN];
    __shared__ float p1[NN][HH][4];
    __shared__ float h[NN][HH];
    __shared__ float hr[NN][RR][CC];
    __shared__ float p2[NN][CC][8];
    __shared__ float o[NN][CC];

    const int t = threadIdx.x;
    const int b = blockIdx.x;
    const int BD = 1024;

    if (b != 0) {
        // ---- reducer: own bins [(b-1)*64, (b-1)*64+64) ----
        const int binl = t & 63;
        const int chunk = t >> 6;            // 0..15
        const int gbin = (b - 1) * 64 + binl;
        int s = 0;
#pragma unroll
        for (int k = 0; k < 16; ++k)
            s += part[(chunk * 16 + k) * NBINS + gbin];
        redacc[chunk][binl] = s;
        __syncthreads();
        if (t < 64) {
            int tot = 0;
#pragma unroll
            for (int c = 0; c < 16; ++c) tot += redacc[c][t];
            gbins[(b - 1) * 64 + t] = tot;
        }
        __threadfence();
        __syncthreads();
        if (t == 0)
            __hip_atomic_fetch_add(&ctrl[0], 1, __ATOMIC_ACQ_REL,
                                   __HIP_MEMORY_SCOPE_AGENT);
        return;
    }

    // ---- block 0: stage weights while reducers work ----
    const float4* W1v = reinterpret_cast<const float4*>(W1);
    for (int i = t; i < RR * NN * HH / 4; i += BD)
        reinterpret_cast<float4*>(w1s)[i] = W1v[i];
    const float4* W2v = reinterpret_cast<const float4*>(W2);
    for (int i = t; i < RR * HH * CC / 4; i += BD)
        reinterpret_cast<float4*>(w2s)[i] = W2v[i];

    // wait for all 49 reducers
    if (t == 0) {
        while (__hip_atomic_load(&ctrl[0], __ATOMIC_ACQUIRE,
                                 __HIP_MEMORY_SCOPE_AGENT) < RED_GRID - 1)
            __builtin_amdgcn_s_sleep(2);
    }
    __syncthreads();
    __threadfence();

    // ---- finish (R10 logic; weights already in LDS) ----
    for (int i = t; i < NN * RR; i += BD) {
        int n = i / RR, r = i % RR;
        const int* gb = gbins + n * (RR * NN) + r * NN;
        int c[NN];
        int tot = 0;
#pragma unroll
        for (int s = 0; s < NN; ++s) { c[s] = gb[s]; tot += c[s]; }
        float inv = 1.0f / (float)(tot > 0 ? tot : 1);
#pragma unroll
        for (int s = 0; s < NN; ++s) cntf[n][r][s] = (float)c[s] * inv;
    }
    __syncthreads();

    // layer 1 partials: (n,j,q), q sums r in [16q,16q+16)
    for (int i = t; i < NN * HH * 4; i += BD) {
        int n = i >> 6;            // HH*4 = 64
        int j = (i >> 2) & (HH - 1);
        int q = i & 3;
        float acc = 0.0f;
        for (int r = q * 16; r < q * 16 + 16; ++r)
            for (int s = 0; s < NN; ++s)
                acc = fmaf(cntf[n][r][s], w1s[(r * NN + s) * HH + j], acc);
        p1[n][j][q] = acc;
    }
    __syncthreads();
    // layer 1 combine: h = relu(root1 + b1 + sum_q p1)
    for (int i = t; i < NN * HH; i += BD) {
        int n = i / HH, j = i % HH;
        float acc = root1[n * HH + j] + b1[j] +
                    p1[n][j][0] + p1[n][j][1] + p1[n][j][2] + p1[n][j][3];
        h[n][j] = fmaxf(acc, 0.0f);
    }
    __syncthreads();

    // hr[s][r][c] = sum_j h[s][j] * W2[r][j][c]
    for (int i = t; i < NN * RR * CC; i += BD) {
        int s = i / (RR * CC);
        int rem = i % (RR * CC);
        int r = rem / CC, c = rem % CC;
        float acc = 0.0f;
        for (int j = 0; j < HH; ++j)
            acc = fmaf(h[s][j], w2s[(r * HH + j) * CC + c], acc);
        hr[s][r][c] = acc;
    }
    __syncthreads();

    // layer 2 partials: (n,c,q), q sums r in [8q,8q+8); q==0 adds root+bias
    for (int i = t; i < NN * CC * 8; i += BD) {
        int n = i >> 6;            // CC*8 = 64
        int c = (i >> 3) & (CC - 1);
        int q = i & 7;
        float acc = 0.0f;
        for (int r = q * 8; r < q * 8 + 8; ++r)
            for (int s = 0; s < NN; ++s)
                acc = fmaf(cntf[n][r][s], hr[s][r][c], acc);
        if (q == 0) {
            for (int j = 0; j < HH; ++j)
                acc = fmaf(h[n][j], root2[j * CC + c], acc);
            acc += b2[c];
        }
        p2[n][c][q] = acc;
    }
    __syncthreads();
    // layer 2 combine
    for (int i = t; i < NN * CC; i += BD) {
        int n = i / CC, c = i % CC;
        float acc = 0.0f;
        for (int q = 0; q < 8; ++q) acc += p2[n][c][q];
        o[n][c] = acc;
    }
    __syncthreads();

    // row-wise log_softmax, one thread per node
    if (t < NN) {
        float m = -1e30f;
        for (int c = 0; c < CC; ++c) m = fmaxf(m, o[t][c]);
        float sum = 0.0f;
        for (int c = 0; c < CC; ++c) sum += __expf(o[t][c] - m);
        float lse = m + __logf(sum);
        for (int c = 0; c < CC; ++c) out[t * CC + c] = o[t][c] - lse;
    }
}

extern "C" void kernel_launch(void* const* d_in, const int* in_sizes, int n_in,
                              void* d_out, int out_size, void* d_ws, size_t ws_size,
                              hipStream_t stream) {
    // input order: x, edge_index, edge_type, W1, root1, b1, W2, root2, b2
    const int* edge_index = (const int*)d_in[1];
    const int* edge_type  = (const int*)d_in[2];
    const float* W1    = (const float*)d_in[3];
    const float* root1 = (const float*)d_in[4];
    const float* b1    = (const float*)d_in[5];
    const float* W2    = (const float*)d_in[6];
    const float* root2 = (const float*)d_in[7];
    const float* b2    = (const float*)d_in[8];
    float* out = (float*)d_out;

    const int E = in_sizes[2];              // num edges
    const int* src = edge_index;            // edge_index[0]
    const int* dst = edge_index + E;        // edge_index[1]

    int* part  = (int*)d_ws;                       // 256 * 3136 ints = 3.2 MB
    int* gbins = part + HIST_GRID * NBINS;         // 3136 ints
    int* ctrl  = gbins + NBINS;                    // ticket counter

    rgcn_hist<<<HIST_GRID, HIST_BLOCK, 0, stream>>>(src, dst, edge_type, E,
                                                    part, ctrl);
    rgcn_redfin<<<RED_GRID, 1024, 0, stream>>>(part, gbins, ctrl,
                                               W1, root1, b1, W2, root2, b2,
                                               out);
}

// Round 12
// 49.594 us; speedup vs baseline: 1.0245x; 1.0245x over previous
//
#include <hip/hip_runtime.h>
#include <hip/hip_bf16.h>

#define NN 7
#define HH 16
#define RR 64
#define CC 8
#define NBINS (NN * RR * NN)   // 3136

#define HIST_BLOCK 1024
#define HIST_GRID  256                      // 1 block/CU, 16 waves/CU, 128-VGPR budget
#define NT (HIST_GRID * HIST_BLOCK)         // 262144 threads
#define NSLOT 8                             // ceil(E4/NT) = 8 for E=8M

// CALIBRATION ROUND: the output depends on bins only via cnt/tot ratios,
// which are scale-invariant -> running the edge loop REPS times multiplies
// all counts by REPS and leaves the output bit-identical. REPS=2 makes
// hist long enough to (a) measure via dur subtraction vs R10 and (b) likely
// surface in rocprof's top-5 with full counters.
#define REPS 2

// ---------------------------------------------------------------------------
// Kernel 1: histogram edges into (dst, rel, src) bins in LDS (R10 rolling
// depth-4 pipeline, run REPS times).
// ---------------------------------------------------------------------------
__global__ __launch_bounds__(HIST_BLOCK) void rgcn_hist(
    const int* __restrict__ src, const int* __restrict__ dst,
    const int* __restrict__ et, int E, int* __restrict__ part) {
    __shared__ int bins[NBINS];
    for (int i = threadIdx.x; i < NBINS; i += HIST_BLOCK) bins[i] = 0;
    __syncthreads();

    const int tid = blockIdx.x * HIST_BLOCK + threadIdx.x;
    const int E4 = E >> 2;
    const int4* s4 = reinterpret_cast<const int4*>(src);
    const int4* d4 = reinterpret_cast<const int4*>(dst);
    const int4* t4 = reinterpret_cast<const int4*>(et);

    for (int rep = 0; rep < REPS; ++rep) {
        if (E4 > 0) {
            for (int base = tid; base < E4; base += NSLOT * NT) {
                int4 S[4], D[4], T[4];
                // prologue: 12 loads back-to-back (slots 0-3, clamped)
#pragma unroll
                for (int k = 0; k < 4; ++k) {
                    int idx = base + k * NT;
                    int cl = idx < E4 ? idx : (E4 - 1);
                    S[k] = s4[cl]; D[k] = d4[cl]; T[k] = t4[cl];
                }
                // steady state: consume slot k, reissue slot k+4
#pragma unroll
                for (int k = 0; k < NSLOT; ++k) {
                    const int slot = k & 3;
                    const int add = (base + k * NT < E4) ? 1 : 0;
                    atomicAdd(&bins[D[slot].x * (RR * NN) + T[slot].x * NN + S[slot].x], add);
                    atomicAdd(&bins[D[slot].y * (RR * NN) + T[slot].y * NN + S[slot].y], add);
                    atomicAdd(&bins[D[slot].z * (RR * NN) + T[slot].z * NN + S[slot].z], add);
                    atomicAdd(&bins[D[slot].w * (RR * NN) + T[slot].w * NN + S[slot].w], add);
                    if (k < NSLOT - 4) {
                        int idx = base + (k + 4) * NT;
                        int cl = idx < E4 ? idx : (E4 - 1);
                        S[slot] = s4[cl]; D[slot] = d4[cl]; T[slot] = t4[cl];
                    }
                }
            }
        }
        // scalar tail (E not multiple of 4; never runs for E=8M)
        for (int e = (E4 << 2) + tid; e < E; e += NT) {
            atomicAdd(&bins[dst[e] * (RR * NN) + et[e] * NN + src[e]], 1);
        }
    }

    __syncthreads();
    // plain coalesced store of the whole private histogram, vectorized
    int4* slice4 = reinterpret_cast<int4*>(part + blockIdx.x * NBINS);
    const int4* bins4 = reinterpret_cast<const int4*>(bins);
    for (int i2 = threadIdx.x; i2 < NBINS / 4; i2 += HIST_BLOCK)
        slice4[i2] = bins4[i2];
}

// ---------------------------------------------------------------------------
// Kernel 1b: reduce HIST_GRID partial histograms -> gbins (R10 verbatim).
// ---------------------------------------------------------------------------
__global__ __launch_bounds__(256) void rgcn_reduce(
    const int* __restrict__ part, int* __restrict__ gbins) {
    __shared__ int acc[4][64];
    const int lane = threadIdx.x & 63;
    const int chunk = threadIdx.x >> 6;      // 0..3
    const int bin = blockIdx.x * 64 + lane;  // 49*64 = 3136 exactly

    int s = 0;
    const int p0 = chunk * (HIST_GRID / 4);
#pragma unroll 8
    for (int k = 0; k < HIST_GRID / 4; ++k)
        s += part[(p0 + k) * NBINS + bin];
    acc[chunk][lane] = s;
    __syncthreads();
    if (chunk == 0)
        gbins[bin] = acc[0][lane] + acc[1][lane] + acc[2][lane] + acc[3][lane];
}

// ---------------------------------------------------------------------------
// Kernel 2: finish (R10 verbatim).
// ---------------------------------------------------------------------------
__global__ __launch_bounds__(1024) void rgcn_finish(
    const int* __restrict__ gbins,
    const float* __restrict__ W1,    // [R][N][H]
    const float* __restrict__ root1, // [N][H]
    const float* __restrict__ b1,    // [H]
    const float* __restrict__ W2,    // [R][H][C]
    const float* __restrict__ root2, // [H][C]
    const float* __restrict__ b2,    // [C]
    float* __restrict__ out) {       // [N][C]
    __shared__ float cntf[NN][RR][NN];
    __shared__ float w1s[RR * NN * HH]; // 7168 floats
    __shared__ float w2s[RR * HH * CC]; // 8192 floats
    __shared__ float p1[NN][HH][4];
    __shared__ float h[NN][HH];
    __shared__ float hr[NN][RR][CC];    // hr[src][r][c]
    __shared__ float p2[NN][CC][8];
    __shared__ float o[NN][CC];

    const int t = threadIdx.x;
    const int BD = 1024;
    const float4* W1v = reinterpret_cast<const float4*>(W1);
    for (int i = t; i < RR * NN * HH / 4; i += BD)
        reinterpret_cast<float4*>(w1s)[i] = W1v[i];
    const float4* W2v = reinterpret_cast<const float4*>(W2);
    for (int i = t; i < RR * HH * CC / 4; i += BD)
        reinterpret_cast<float4*>(w2s)[i] = W2v[i];
    for (int i = t; i < NN * RR; i += BD) {
        int n = i / RR, r = i % RR;
        const int* gb = gbins + n * (RR * NN) + r * NN;
        int c[NN];
        int tot = 0;
#pragma unroll
        for (int s = 0; s < NN; ++s) { c[s] = gb[s]; tot += c[s]; }
        float inv = 1.0f / (float)(tot > 0 ? tot : 1);
#pragma unroll
        for (int s = 0; s < NN; ++s) cntf[n][r][s] = (float)c[s] * inv;
    }
    __syncthreads();

    // layer 1 partials: (n,j,q), q sums r in [16q,16q+16)
    for (int i = t; i < NN * HH * 4; i += BD) {
        int n = i >> 6;            // HH*4 = 64
        int j = (i >> 2) & (HH - 1);
        int q = i & 3;
        float acc = 0.0f;
        for (int r = q * 16; r < q * 16 + 16; ++r)
            for (int s = 0; s < NN; ++s)
                acc = fmaf(cntf[n][r][s], w1s[(r * NN + s) * HH + j], acc);
        p1[n][j][q] = acc;
    }
    __syncthreads();
    for (int i = t; i < NN * HH; i += BD) {
        int n = i / HH, j = i % HH;
        float acc = root1[n * HH + j] + b1[j] +
                    p1[n][j][0] + p1[n][j][1] + p1[n][j][2] + p1[n][j][3];
        h[n][j] = fmaxf(acc, 0.0f);
    }
    __syncthreads();

    // hr[s][r][c] = sum_j h[s][j] * W2[r][j][c]
    for (int i = t; i < NN * RR * CC; i += BD) {
        int s = i / (RR * CC);
        int rem = i % (RR * CC);
        int r = rem / CC, c = rem % CC;
        float acc = 0.0f;
        for (int j = 0; j < HH; ++j)
            acc = fmaf(h[s][j], w2s[(r * HH + j) * CC + c], acc);
        hr[s][r][c] = acc;
    }
    __syncthreads();

    // layer 2 partials: (n,c,q), q sums r in [8q,8q+8); q==0 adds root+bias
    for (int i = t; i < NN * CC * 8; i += BD) {
        int n = i >> 6;            // CC*8 = 64
        int c = (i >> 3) & (CC - 1);
        int q = i & 7;
        float acc = 0.0f;
        for (int r = q * 8; r < q * 8 + 8; ++r)
            for (int s = 0; s < NN; ++s)
                acc = fmaf(cntf[n][r][s], hr[s][r][c], acc);
        if (q == 0) {
            for (int j = 0; j < HH; ++j)
                acc = fmaf(h[n][j], root2[j * CC + c], acc);
            acc += b2[c];
        }
        p2[n][c][q] = acc;
    }
    __syncthreads();
    for (int i = t; i < NN * CC; i += BD) {
        int n = i / CC, c = i % CC;
        float acc = 0.0f;
        for (int q = 0; q < 8; ++q) acc += p2[n][c][q];
        o[n][c] = acc;
    }
    __syncthreads();

    // row-wise log_softmax, one thread per node
    if (t < NN) {
        float m = -1e30f;
        for (int c = 0; c < CC; ++c) m = fmaxf(m, o[t][c]);
        float sum = 0.0f;
        for (int c = 0; c < CC; ++c) sum += __expf(o[t][c] - m);
        float lse = m + __logf(sum);
        for (int c = 0; c < CC; ++c) out[t * CC + c] = o[t][c] - lse;
    }
}

extern "C" void kernel_launch(void* const* d_in, const int* in_sizes, int n_in,
                              void* d_out, int out_size, void* d_ws, size_t ws_size,
                              hipStream_t stream) {
    // input order: x, edge_index, edge_type, W1, root1, b1, W2, root2, b2
    const int* edge_index = (const int*)d_in[1];
    const int* edge_type  = (const int*)d_in[2];
    const float* W1    = (const float*)d_in[3];
    const float* root1 = (const float*)d_in[4];
    const float* b1    = (const float*)d_in[5];
    const float* W2    = (const float*)d_in[6];
    const float* root2 = (const float*)d_in[7];
    const float* b2    = (const float*)d_in[8];
    float* out = (float*)d_out;

    const int E = in_sizes[2];              // num edges
    const int* src = edge_index;            // edge_index[0]
    const int* dst = edge_index + E;        // edge_index[1]

    int* part  = (int*)d_ws;                       // 256 * 3136 ints = 3.2 MB
    int* gbins = part + HIST_GRID * NBINS;         // 3136 ints

    rgcn_hist<<<HIST_GRID, HIST_BLOCK, 0, stream>>>(src, dst, edge_type, E, part);
    rgcn_reduce<<<49, 256, 0, stream>>>(part, gbins);
    rgcn_finish<<<1, 1024, 0, stream>>>(gbins, W1, root1, b1, W2, root2, b2, out);
}

// Round 13
// 35.705 us; speedup vs baseline: 1.4230x; 1.3890x over previous
//
#include <hip/hip_runtime.h>
#include <hip/hip_bf16.h>

#define NN 7
#define HH 16
#define RR 64
#define CC 8
#define NBINS (NN * RR * NN)   // 3136

#define HIST_BLOCK 1024
#define HIST_GRID  256                      // 1 block/CU, 16 waves/CU, 128-VGPR budget
#define NT (HIST_GRID * HIST_BLOCK)         // 262144 threads
#define NSLOT 8                             // ceil(E4/NT) = 8 for E=8M

#define LOAD_SLOT(k, idx)  { S[k] = s4[idx]; D[k] = d4[idx]; T[k] = t4[idx]; }
#define ATOM_SLOT(k, add)                                                    \
    atomicAdd(&bins[D[k].x * (RR * NN) + T[k].x * NN + S[k].x], add);        \
    atomicAdd(&bins[D[k].y * (RR * NN) + T[k].y * NN + S[k].y], add);        \
    atomicAdd(&bins[D[k].z * (RR * NN) + T[k].z * NN + S[k].z], add);        \
    atomicAdd(&bins[D[k].w * (RR * NN) + T[k].w * NN + S[k].w], add);

// ---------------------------------------------------------------------------
// Kernel 1: histogram edges into (dst, rel, src) LDS bins.
// R12 calibration showed VGPR_Count=32: the compiler register-minimized every
// prior "pipeline" into depth-1 serial form (load->wait->atomics), capping
// HBM at ~2.9 TB/s. Fix: pin the schedule with sched_barrier(0) fences so
// all 24 dwordx4 loads are issued before any atomic -> values stay live ->
// allocator must hold ~96 data VGPRs (fits 128 cap @ 16 waves/CU).
// Atomics 0-3 then run with slots 4-7 still in flight (counted-vmcnt).
// ---------------------------------------------------------------------------
__global__ __launch_bounds__(HIST_BLOCK) void rgcn_hist(
    const int* __restrict__ src, const int* __restrict__ dst,
    const int* __restrict__ et, int E, int* __restrict__ part) {
    __shared__ int bins[NBINS];
    for (int i = threadIdx.x; i < NBINS; i += HIST_BLOCK) bins[i] = 0;
    __syncthreads();

    const int tid = blockIdx.x * HIST_BLOCK + threadIdx.x;
    const int E4 = E >> 2;
    const int4* s4 = reinterpret_cast<const int4*>(src);
    const int4* d4 = reinterpret_cast<const int4*>(dst);
    const int4* t4 = reinterpret_cast<const int4*>(et);

    for (int base = tid; base < E4; base += NSLOT * NT) {
        int4 S[NSLOT], D[NSLOT], T[NSLOT];
        if (base + (NSLOT - 1) * NT < E4) {
            // fast path (63% of threads at E=8M): no clamp, no predicate
#pragma unroll
            for (int k = 0; k < 4; ++k) LOAD_SLOT(k, base + k * NT)
            __builtin_amdgcn_sched_barrier(0);
#pragma unroll
            for (int k = 4; k < NSLOT; ++k) LOAD_SLOT(k, base + k * NT)
            __builtin_amdgcn_sched_barrier(0);
#pragma unroll
            for (int k = 0; k < 4; ++k) { ATOM_SLOT(k, 1) }
            __builtin_amdgcn_sched_barrier(0);
#pragma unroll
            for (int k = 4; k < NSLOT; ++k) { ATOM_SLOT(k, 1) }
        } else {
            // slow path: clamp OOB addresses, predicate addend to 0
#pragma unroll
            for (int k = 0; k < 4; ++k) {
                int idx = base + k * NT;
                LOAD_SLOT(k, idx < E4 ? idx : (E4 - 1))
            }
            __builtin_amdgcn_sched_barrier(0);
#pragma unroll
            for (int k = 4; k < NSLOT; ++k) {
                int idx = base + k * NT;
                LOAD_SLOT(k, idx < E4 ? idx : (E4 - 1))
            }
            __builtin_amdgcn_sched_barrier(0);
#pragma unroll
            for (int k = 0; k < 4; ++k) {
                const int add = (base + k * NT < E4) ? 1 : 0;
                ATOM_SLOT(k, add)
            }
            __builtin_amdgcn_sched_barrier(0);
#pragma unroll
            for (int k = 4; k < NSLOT; ++k) {
                const int add = (base + k * NT < E4) ? 1 : 0;
                ATOM_SLOT(k, add)
            }
        }
    }
    // scalar tail (E not multiple of 4; never runs for E=8M)
    for (int e = (E4 << 2) + tid; e < E; e += NT) {
        atomicAdd(&bins[dst[e] * (RR * NN) + et[e] * NN + src[e]], 1);
    }

    __syncthreads();
    // plain coalesced store of the whole private histogram, vectorized
    int4* slice4 = reinterpret_cast<int4*>(part + blockIdx.x * NBINS);
    const int4* bins4 = reinterpret_cast<const int4*>(bins);
    for (int i2 = threadIdx.x; i2 < NBINS / 4; i2 += HIST_BLOCK)
        slice4[i2] = bins4[i2];
}

// ---------------------------------------------------------------------------
// Kernel 1b: reduce HIST_GRID partial histograms -> gbins (R10 verbatim).
// ---------------------------------------------------------------------------
__global__ __launch_bounds__(256) void rgcn_reduce(
    const int* __restrict__ part, int* __restrict__ gbins) {
    __shared__ int acc[4][64];
    const int lane = threadIdx.x & 63;
    const int chunk = threadIdx.x >> 6;      // 0..3
    const int bin = blockIdx.x * 64 + lane;  // 49*64 = 3136 exactly

    int s = 0;
    const int p0 = chunk * (HIST_GRID / 4);
#pragma unroll 8
    for (int k = 0; k < HIST_GRID / 4; ++k)
        s += part[(p0 + k) * NBINS + bin];
    acc[chunk][lane] = s;
    __syncthreads();
    if (chunk == 0)
        gbins[bin] = acc[0][lane] + acc[1][lane] + acc[2][lane] + acc[3][lane];
}

// ---------------------------------------------------------------------------
// Kernel 2: finish (R10 verbatim).
// ---------------------------------------------------------------------------
__global__ __launch_bounds__(1024) void rgcn_finish(
    const int* __restrict__ gbins,
    const float* __restrict__ W1,    // [R][N][H]
    const float* __restrict__ root1, // [N][H]
    const float* __restrict__ b1,    // [H]
    const float* __restrict__ W2,    // [R][H][C]
    const float* __restrict__ root2, // [H][C]
    const float* __restrict__ b2,    // [C]
    float* __restrict__ out) {       // [N][C]
    __shared__ float cntf[NN][RR][NN];
    __shared__ float w1s[RR * NN * HH]; // 7168 floats
    __shared__ float w2s[RR * HH * CC]; // 8192 floats
    __shared__ float p1[NN][HH][4];
    __shared__ float h[NN][HH];
    __shared__ float hr[NN][RR][CC];    // hr[src][r][c]
    __shared__ float p2[NN][CC][8];
    __shared__ float o[NN][CC];

    const int t = threadIdx.x;
    const int BD = 1024;
    const float4* W1v = reinterpret_cast<const float4*>(W1);
    for (int i = t; i < RR * NN * HH / 4; i += BD)
        reinterpret_cast<float4*>(w1s)[i] = W1v[i];
    const float4* W2v = reinterpret_cast<const float4*>(W2);
    for (int i = t; i < RR * HH * CC / 4; i += BD)
        reinterpret_cast<float4*>(w2s)[i] = W2v[i];
    for (int i = t; i < NN * RR; i += BD) {
        int n = i / RR, r = i % RR;
        const int* gb = gbins + n * (RR * NN) + r * NN;
        int c[NN];
        int tot = 0;
#pragma unroll
        for (int s = 0; s < NN; ++s) { c[s] = gb[s]; tot += c[s]; }
        float inv = 1.0f / (float)(tot > 0 ? tot : 1);
#pragma unroll
        for (int s = 0; s < NN; ++s) cntf[n][r][s] = (float)c[s] * inv;
    }
    __syncthreads();

    // layer 1 partials: (n,j,q), q sums r in [16q,16q+16)
    for (int i = t; i < NN * HH * 4; i += BD) {
        int n = i >> 6;            // HH*4 = 64
        int j = (i >> 2) & (HH - 1);
        int q = i & 3;
        float acc = 0.0f;
        for (int r = q * 16; r < q * 16 + 16; ++r)
            for (int s = 0; s < NN; ++s)
                acc = fmaf(cntf[n][r][s], w1s[(r * NN + s) * HH + j], acc);
        p1[n][j][q] = acc;
    }
    __syncthreads();
    for (int i = t; i < NN * HH; i += BD) {
        int n = i / HH, j = i % HH;
        float acc = root1[n * HH + j] + b1[j] +
                    p1[n][j][0] + p1[n][j][1] + p1[n][j][2] + p1[n][j][3];
        h[n][j] = fmaxf(acc, 0.0f);
    }
    __syncthreads();

    // hr[s][r][c] = sum_j h[s][j] * W2[r][j][c]
    for (int i = t; i < NN * RR * CC; i += BD) {
        int s = i / (RR * CC);
        int rem = i % (RR * CC);
        int r = rem / CC, c = rem % CC;
        float acc = 0.0f;
        for (int j = 0; j < HH; ++j)
            acc = fmaf(h[s][j], w2s[(r * HH + j) * CC + c], acc);
        hr[s][r][c] = acc;
    }
    __syncthreads();

    // layer 2 partials: (n,c,q), q sums r in [8q,8q+8); q==0 adds root+bias
    for (int i = t; i < NN * CC * 8; i += BD) {
        int n = i >> 6;            // CC*8 = 64
        int c = (i >> 3) & (CC - 1);
        int q = i & 7;
        float acc = 0.0f;
        for (int r = q * 8; r < q * 8 + 8; ++r)
            for (int s = 0; s < NN; ++s)
                acc = fmaf(cntf[n][r][s], hr[s][r][c], acc);
        if (q == 0) {
            for (int j = 0; j < HH; ++j)
                acc = fmaf(h[n][j], root2[j * CC + c], acc);
            acc += b2[c];
        }
        p2[n][c][q] = acc;
    }
    __syncthreads();
    for (int i = t; i < NN * CC; i += BD) {
        int n = i / CC, c = i % CC;
        float acc = 0.0f;
        for (int q = 0; q < 8; ++q) acc += p2[n][c][q];
        o[n][c] = acc;
    }
    __syncthreads();

    // row-wise log_softmax, one thread per node
    if (t < NN) {
        float m = -1e30f;
        for (int c = 0; c < CC; ++c) m = fmaxf(m, o[t][c]);
        float sum = 0.0f;
        for (int c = 0; c < CC; ++c) sum += __expf(o[t][c] - m);
        float lse = m + __logf(sum);
        for (int c = 0; c < CC; ++c) out[t * CC + c] = o[t][c] - lse;
    }
}

extern "C" void kernel_launch(void* const* d_in, const int* in_sizes, int n_in,
                              void* d_out, int out_size, void* d_ws, size_t ws_size,
                              hipStream_t stream) {
    // input order: x, edge_index, edge_type, W1, root1, b1, W2, root2, b2
    const int* edge_index = (const int*)d_in[1];
    const int* edge_type  = (const int*)d_in[2];
    const float* W1    = (const float*)d_in[3];
    const float* root1 = (const float*)d_in[4];
    const float* b1    = (const float*)d_in[5];
    const float* W2    = (const float*)d_in[6];
    const float* root2 = (const float*)d_in[7];
    const float* b2    = (const float*)d_in[8];
    float* out = (float*)d_out;

    const int E = in_sizes[2];              // num edges
    const int* src = edge_index;            // edge_index[0]
    const int* dst = edge_index + E;        // edge_index[1]

    int* part  = (int*)d_ws;                       // 256 * 3136 ints = 3.2 MB
    int* gbins = part + HIST_GRID * NBINS;         // 3136 ints

    rgcn_hist<<<HIST_GRID, HIST_BLOCK, 0, stream>>>(src, dst, edge_type, E, part);
    rgcn_reduce<<<49, 256, 0, stream>>>(part, gbins);
    rgcn_finish<<<1, 1024, 0, stream>>>(gbins, W1, root1, b1, W2, root2, b2, out);
}

// Round 14
// 35.376 us; speedup vs baseline: 1.4362x; 1.0093x over previous
//
#include <hip/hip_runtime.h>
#include <hip/hip_bf16.h>

#define NN 7
#define HH 16
#define RR 64
#define CC 8
#define NBINS (NN * RR * NN)   // 3136

#define HIST_BLOCK 1024
#define HIST_GRID  256                      // 1 block/CU, 16 waves/CU, 128-VGPR cap
#define NT (HIST_GRID * HIST_BLOCK)         // 262144 threads
#define NSLOT 8                             // ceil(E4/NT) = 8 for E=8M -> one barrage

typedef int v4i __attribute__((ext_vector_type(4)));

// Volatile asm load: compiler CANNOT serialize, sink, or register-minimize
// this barrage (R12 proved it collapsed every source-level pipeline to
// VGPR_Count=32 / depth-1). 24 loads issue in program order; waits are
// explicit counted vmcnt (AITER/T4 pattern).
#define GLOAD(dest, p) \
    asm volatile("global_load_dwordx4 %0, %1, off" : "=v"(dest) : "v"(p))

// ---------------------------------------------------------------------------
// Kernel 1: histogram edges into (dst, rel, src) LDS bins.
// Single-phase 8-slot barrage: 24 global_load_dwordx4 issued back-to-back
// via inline asm (96 data VGPRs architecturally live), then
// vmcnt(12) -> atomics slots 0-3 (12 loads still in flight) ->
// vmcnt(0)  -> atomics slots 4-7. LDS atomics are memory ops, so they
// cannot hoist past the memory-clobbered waitcnt asm (guide rule #18).
// ---------------------------------------------------------------------------
__global__ __launch_bounds__(HIST_BLOCK) void rgcn_hist(
    const int* __restrict__ src, const int* __restrict__ dst,
    const int* __restrict__ et, int E, int* __restrict__ part) {
    __shared__ int bins[NBINS];
    for (int i = threadIdx.x; i < NBINS; i += HIST_BLOCK) bins[i] = 0;
    __syncthreads();

    const int tid = blockIdx.x * HIST_BLOCK + threadIdx.x;
    const int E4 = E >> 2;
    const v4i* s4 = reinterpret_cast<const v4i*>(src);
    const v4i* d4 = reinterpret_cast<const v4i*>(dst);
    const v4i* t4 = reinterpret_cast<const v4i*>(et);

    for (int base = tid; base < E4; base += NSLOT * NT) {
        v4i S[NSLOT], D[NSLOT], T[NSLOT];
        int ix[NSLOT];
#pragma unroll
        for (int k = 0; k < NSLOT; ++k) {
            int raw = base + k * NT;
            ix[k] = raw < E4 ? raw : (E4 - 1);   // clamp OOB (branch-uniform)
        }
        // issue all 24 loads back-to-back, program order
#pragma unroll
        for (int k = 0; k < NSLOT; ++k) {
            GLOAD(S[k], s4 + ix[k]);
            GLOAD(D[k], d4 + ix[k]);
            GLOAD(T[k], t4 + ix[k]);
        }
        // first 12 loads (slots 0-3) done; 12 still in flight
        asm volatile("s_waitcnt vmcnt(12)" ::: "memory");
        __builtin_amdgcn_sched_barrier(0);
#pragma unroll
        for (int k = 0; k < 4; ++k) {
            const int add = (base + k * NT < E4) ? 1 : 0;   // predicate OOB
            atomicAdd(&bins[D[k][0] * (RR * NN) + T[k][0] * NN + S[k][0]], add);
            atomicAdd(&bins[D[k][1] * (RR * NN) + T[k][1] * NN + S[k][1]], add);
            atomicAdd(&bins[D[k][2] * (RR * NN) + T[k][2] * NN + S[k][2]], add);
            atomicAdd(&bins[D[k][3] * (RR * NN) + T[k][3] * NN + S[k][3]], add);
        }
        asm volatile("s_waitcnt vmcnt(0)" ::: "memory");
        __builtin_amdgcn_sched_barrier(0);
#pragma unroll
        for (int k = 4; k < NSLOT; ++k) {
            const int add = (base + k * NT < E4) ? 1 : 0;
            atomicAdd(&bins[D[k][0] * (RR * NN) + T[k][0] * NN + S[k][0]], add);
            atomicAdd(&bins[D[k][1] * (RR * NN) + T[k][1] * NN + S[k][1]], add);
            atomicAdd(&bins[D[k][2] * (RR * NN) + T[k][2] * NN + S[k][2]], add);
            atomicAdd(&bins[D[k][3] * (RR * NN) + T[k][3] * NN + S[k][3]], add);
        }
    }
    // scalar tail (E not multiple of 4; never runs for E=8M)
    for (int e = (E4 << 2) + tid; e < E; e += NT) {
        atomicAdd(&bins[dst[e] * (RR * NN) + et[e] * NN + src[e]], 1);
    }

    __syncthreads();
    // plain coalesced store of the whole private histogram, vectorized
    int4* slice4 = reinterpret_cast<int4*>(part + blockIdx.x * NBINS);
    const int4* bins4 = reinterpret_cast<const int4*>(bins);
    for (int i2 = threadIdx.x; i2 < NBINS / 4; i2 += HIST_BLOCK)
        slice4[i2] = bins4[i2];
}

// ---------------------------------------------------------------------------
// Kernel 1b: reduce HIST_GRID partial histograms -> gbins (R10 verbatim).
// ---------------------------------------------------------------------------
__global__ __launch_bounds__(256) void rgcn_reduce(
    const int* __restrict__ part, int* __restrict__ gbins) {
    __shared__ int acc[4][64];
    const int lane = threadIdx.x & 63;
    const int chunk = threadIdx.x >> 6;      // 0..3
    const int bin = blockIdx.x * 64 + lane;  // 49*64 = 3136 exactly

    int s = 0;
    const int p0 = chunk * (HIST_GRID / 4);
#pragma unroll 8
    for (int k = 0; k < HIST_GRID / 4; ++k)
        s += part[(p0 + k) * NBINS + bin];
    acc[chunk][lane] = s;
    __syncthreads();
    if (chunk == 0)
        gbins[bin] = acc[0][lane] + acc[1][lane] + acc[2][lane] + acc[3][lane];
}

// ---------------------------------------------------------------------------
// Kernel 2: finish (R10 verbatim).
// ---------------------------------------------------------------------------
__global__ __launch_bounds__(1024) void rgcn_finish(
    const int* __restrict__ gbins,
    const float* __restrict__ W1,    // [R][N][H]
    const float* __restrict__ root1, // [N][H]
    const float* __restrict__ b1,    // [H]
    const float* __restrict__ W2,    // [R][H][C]
    const float* __restrict__ root2, // [H][C]
    const float* __restrict__ b2,    // [C]
    float* __restrict__ out) {       // [N][C]
    __shared__ float cntf[NN][RR][NN];
    __shared__ float w1s[RR * NN * HH]; // 7168 floats
    __shared__ float w2s[RR * HH * CC]; // 8192 floats
    __shared__ float p1[NN][HH][4];
    __shared__ float h[NN][HH];
    __shared__ float hr[NN][RR][CC];    // hr[src][r][c]
    __shared__ float p2[NN][CC][8];
    __shared__ float o[NN][CC];

    const int t = threadIdx.x;
    const int BD = 1024;
    const float4* W1v = reinterpret_cast<const float4*>(W1);
    for (int i = t; i < RR * NN * HH / 4; i += BD)
        reinterpret_cast<float4*>(w1s)[i] = W1v[i];
    const float4* W2v = reinterpret_cast<const float4*>(W2);
    for (int i = t; i < RR * HH * CC / 4; i += BD)
        reinterpret_cast<float4*>(w2s)[i] = W2v[i];
    for (int i = t; i < NN * RR; i += BD) {
        int n = i / RR, r = i % RR;
        const int* gb = gbins + n * (RR * NN) + r * NN;
        int c[NN];
        int tot = 0;
#pragma unroll
        for (int s = 0; s < NN; ++s) { c[s] = gb[s]; tot += c[s]; }
        float inv = 1.0f / (float)(tot > 0 ? tot : 1);
#pragma unroll
        for (int s = 0; s < NN; ++s) cntf[n][r][s] = (float)c[s] * inv;
    }
    __syncthreads();

    // layer 1 partials: (n,j,q), q sums r in [16q,16q+16)
    for (int i = t; i < NN * HH * 4; i += BD) {
        int n = i >> 6;            // HH*4 = 64
        int j = (i >> 2) & (HH - 1);
        int q = i & 3;
        float acc = 0.0f;
        for (int r = q * 16; r < q * 16 + 16; ++r)
            for (int s = 0; s < NN; ++s)
                acc = fmaf(cntf[n][r][s], w1s[(r * NN + s) * HH + j], acc);
        p1[n][j][q] = acc;
    }
    __syncthreads();
    for (int i = t; i < NN * HH; i += BD) {
        int n = i / HH, j = i % HH;
        float acc = root1[n * HH + j] + b1[j] +
                    p1[n][j][0] + p1[n][j][1] + p1[n][j][2] + p1[n][j][3];
        h[n][j] = fmaxf(acc, 0.0f);
    }
    __syncthreads();

    // hr[s][r][c] = sum_j h[s][j] * W2[r][j][c]
    for (int i = t; i < NN * RR * CC; i += BD) {
        int s = i / (RR * CC);
        int rem = i % (RR * CC);
        int r = rem / CC, c = rem % CC;
        float acc = 0.0f;
        for (int j = 0; j < HH; ++j)
            acc = fmaf(h[s][j], w2s[(r * HH + j) * CC + c], acc);
        hr[s][r][c] = acc;
    }
    __syncthreads();

    // layer 2 partials: (n,c,q), q sums r in [8q,8q+8); q==0 adds root+bias
    for (int i = t; i < NN * CC * 8; i += BD) {
        int n = i >> 6;            // CC*8 = 64
        int c = (i >> 3) & (CC - 1);
        int q = i & 7;
        float acc = 0.0f;
        for (int r = q * 8; r < q * 8 + 8; ++r)
            for (int s = 0; s < NN; ++s)
                acc = fmaf(cntf[n][r][s], hr[s][r][c], acc);
        if (q == 0) {
            for (int j = 0; j < HH; ++j)
                acc = fmaf(h[n][j], root2[j * CC + c], acc);
            acc += b2[c];
        }
        p2[n][c][q] = acc;
    }
    __syncthreads();
    for (int i = t; i < NN * CC; i += BD) {
        int n = i / CC, c = i % CC;
        float acc = 0.0f;
        for (int q = 0; q < 8; ++q) acc += p2[n][c][q];
        o[n][c] = acc;
    }
    __syncthreads();

    // row-wise log_softmax, one thread per node
    if (t < NN) {
        float m = -1e30f;
        for (int c = 0; c < CC; ++c) m = fmaxf(m, o[t][c]);
        float sum = 0.0f;
        for (int c = 0; c < CC; ++c) sum += __expf(o[t][c] - m);
        float lse = m + __logf(sum);
        for (int c = 0; c < CC; ++c) out[t * CC + c] = o[t][c] - lse;
    }
}

extern "C" void kernel_launch(void* const* d_in, const int* in_sizes, int n_in,
                              void* d_out, int out_size, void* d_ws, size_t ws_size,
                              hipStream_t stream) {
    // input order: x, edge_index, edge_type, W1, root1, b1, W2, root2, b2
    const int* edge_index = (const int*)d_in[1];
    const int* edge_type  = (const int*)d_in[2];
    const float* W1    = (const float*)d_in[3];
    const float* root1 = (const float*)d_in[4];
    const float* b1    = (const float*)d_in[5];
    const float* W2    = (const float*)d_in[6];
    const float* root2 = (const float*)d_in[7];
    const float* b2    = (const float*)d_in[8];
    float* out = (float*)d_out;

    const int E = in_sizes[2];              // num edges
    const int* src = edge_index;            // edge_index[0]
    const int* dst = edge_index + E;        // edge_index[1]

    int* part  = (int*)d_ws;                       // 256 * 3136 ints = 3.2 MB
    int* gbins = part + HIST_GRID * NBINS;         // 3136 ints

    rgcn_hist<<<HIST_GRID, HIST_BLOCK, 0, stream>>>(src, dst, edge_type, E, part);
    rgcn_reduce<<<49, 256, 0, stream>>>(part, gbins);
    rgcn_finish<<<1, 1024, 0, stream>>>(gbins, W1, root1, b1, W2, root2, b2, out);
}